// Round 8
// baseline (304.625 us; speedup 1.0000x reference)
//
#include <hip/hip_runtime.h>
#include <hip/hip_bf16.h>
#include <stdint.h>

#define TOKS  2048
#define HID   2048
#define ITR   1024
#define NEXP  8
#define NROWS 4096   // TOKS * TOP_K

typedef __attribute__((ext_vector_type(4))) float f32x4;
typedef __attribute__((ext_vector_type(8))) __bf16 bf16x8;
typedef __attribute__((ext_vector_type(8))) unsigned short u16x8;

__device__ __forceinline__ unsigned short f2bf(float f) {
    union { float f; uint32_t u; } c; c.f = f;
    return (unsigned short)((c.u + 0x7FFFu + ((c.u >> 16) & 1u)) >> 16);
}

// async global->LDS, 16B per lane. LDS dest = wave-uniform base + lane*16 (HW).
__device__ __forceinline__ void gll16(const unsigned short* g, unsigned short* l) {
    __builtin_amdgcn_global_load_lds(
        (const __attribute__((address_space(1))) unsigned int*)g,
        (__attribute__((address_space(3))) unsigned int*)l,
        16, 0, 0);
}

// ---------------- init ----------------
__global__ __launch_bounds__(64) void zero_counts_kernel(int* counts) {
    if (threadIdx.x < NEXP) counts[threadIdx.x] = 0;
}

__global__ __launch_bounds__(256) void zero_out_kernel(float* __restrict__ out) {
    const int i = (blockIdx.x * 256 + threadIdx.x) * 4;
    *(f32x4*)&out[i] = (f32x4){0.f, 0.f, 0.f, 0.f};
}

// ---------------- fp32 -> bf16 convert ----------------
__global__ __launch_bounds__(256) void cvt_kernel(const float* __restrict__ src,
                                                  unsigned short* __restrict__ dst,
                                                  int n8) {
    int i = blockIdx.x * 256 + threadIdx.x;
    const int stride = gridDim.x * 256;
    for (; i < n8; i += stride) {
        const f32x4* p = (const f32x4*)(src + (size_t)i * 8);
        f32x4 a = p[0], b = p[1];
        u16x8 o;
#pragma unroll
        for (int j = 0; j < 4; ++j) { o[j] = f2bf(a[j]); o[4 + j] = f2bf(b[j]); }
        *(u16x8*)(dst + (size_t)i * 8) = o;
    }
}

// ---------------- router (also emits bf16 copy of x) ----------------
__global__ __launch_bounds__(64) void router_kernel(const float* __restrict__ x,
                                                    const float* __restrict__ gw,
                                                    unsigned short* __restrict__ xb,
                                                    int* __restrict__ topk_id,
                                                    float* __restrict__ topk_w,
                                                    int* __restrict__ counts) {
    const int t = blockIdx.x;
    const int lane = threadIdx.x;
    float acc[NEXP];
#pragma unroll
    for (int e = 0; e < NEXP; ++e) acc[e] = 0.f;
    const float* xr = x + (size_t)t * HID;
    unsigned short* xbr = xb + (size_t)t * HID;
    for (int s = lane; s < HID; s += 64) {
        float xv = xr[s];
        xbr[s] = f2bf(xv);
#pragma unroll
        for (int e = 0; e < NEXP; ++e) acc[e] += xv * gw[e * HID + s];
    }
#pragma unroll
    for (int e = 0; e < NEXP; ++e) {
        float v = acc[e];
        for (int off = 32; off > 0; off >>= 1) v += __shfl_down(v, off, 64);
        acc[e] = v;
    }
    if (lane == 0) {
        float m0 = -1e30f, m1 = -1e30f; int i0 = 0, i1 = 0;
#pragma unroll
        for (int e = 0; e < NEXP; ++e) {
            float v = acc[e];
            if (v > m0) { m1 = m0; i1 = i0; m0 = v; i0 = e; }
            else if (v > m1) { m1 = v; i1 = e; }
        }
        float w0 = 1.f / (1.f + expf(m1 - m0));
        float w1 = 1.f - w0;
        topk_id[t * 2] = i0; topk_id[t * 2 + 1] = i1;
        topk_w[t * 2] = w0;  topk_w[t * 2 + 1] = w1;
        atomicAdd(&counts[i0], 1);
        atomicAdd(&counts[i1], 1);
    }
}

__global__ void offsets_kernel(const int* __restrict__ counts,
                               int* __restrict__ offsets,
                               int* __restrict__ cursors) {
    if (threadIdx.x == 0) {
        int s = 0;
        for (int e = 0; e < NEXP; ++e) { offsets[e] = s; cursors[e] = s; s += counts[e]; }
        offsets[NEXP] = s;
    }
}

__global__ __launch_bounds__(256) void assign_kernel(const int* __restrict__ topk_id,
                                                     const float* __restrict__ topk_w,
                                                     int* __restrict__ cursors,
                                                     int* __restrict__ sorted_tok,
                                                     float* __restrict__ row_w) {
    const int p = blockIdx.x * 256 + threadIdx.x;
    if (p >= NROWS) return;
    const int e = topk_id[p];
    const int pos = atomicAdd(&cursors[e], 1);
    sorted_tok[pos] = p >> 1;
    row_w[pos] = topk_w[p];
}

// ---------------- GEMM1: gathered xb @ wsb[e]^T, fused SiLU*up ----------------
// 64 A-rows x (64 gate + 64 up) B-rows, BK=32, triple-buffer (36 KB -> 4 blocks/CU),
// one barrier + counted vmcnt(3) per K-step (round-6 proven loop skeleton).
__global__ __launch_bounds__(256) void gemm1_kernel(const unsigned short* __restrict__ Wb,
                                                    const unsigned short* __restrict__ Xb,
                                                    const int* __restrict__ offsets,
                                                    const int* __restrict__ counts,
                                                    const int* __restrict__ sorted_tok,
                                                    unsigned short* __restrict__ act) {
    const int e = blockIdx.z, mt = blockIdx.y, nt = blockIdx.x;
    const int cnt = counts[e];
    if (mt * 64 >= cnt) return;
    const int offs = offsets[e];
    const int tid = threadIdx.x, lane = tid & 63, wid = tid >> 6;
    const int wr = wid >> 1, wc = wid & 1;

    __shared__ unsigned short sA[3][64 * 32];
    __shared__ unsigned short sB[3][128 * 32];

    // write-side: lane covers row (tid>>2), slot tid&3; global chunk = slot ^ (row&3)
    const int swz = (((tid & 3) ^ ((tid >> 2) & 3))) * 8;
    int ar = mt * 64 + (tid >> 2);
    if (ar >= cnt) ar = cnt - 1;
    const int tok = sorted_tok[offs + ar];
    const unsigned short* aSrc0 = Xb + (size_t)tok * HID + swz;
    const unsigned short* wBase = Wb + (size_t)e * (2 * ITR) * HID;
    const unsigned short* bSrc0 = wBase + (size_t)(nt * 64 + (tid >> 2)) * HID + swz;        // gate
    const unsigned short* bSrc1 = wBase + (size_t)(ITR + nt * 64 + (tid >> 2)) * HID + swz;  // up
    const int ldsOff0 = wid * 16 * 32;
    const int ldsOff1 = (64 + wid * 16) * 32;

    f32x4 accg[2][2], accu[2][2];
#pragma unroll
    for (int i = 0; i < 2; ++i)
#pragma unroll
        for (int j = 0; j < 2; ++j) {
            accg[i][j] = (f32x4){0.f, 0.f, 0.f, 0.f};
            accu[i][j] = (f32x4){0.f, 0.f, 0.f, 0.f};
        }

#define G1_STAGE(ks) do {                                  \
        const int k0_ = (ks) * 32;                         \
        unsigned short* a_ = sA[(ks) % 3];                 \
        unsigned short* b_ = sB[(ks) % 3];                 \
        gll16(aSrc0 + k0_, a_ + ldsOff0);                  \
        gll16(bSrc0 + k0_, b_ + ldsOff0);                  \
        gll16(bSrc1 + k0_, b_ + ldsOff1);                  \
    } while (0)

    G1_STAGE(0);
    G1_STAGE(1);

    const int fr = lane & 15, fq = lane >> 4;
    const int sfo = (fq ^ (fr & 3)) * 8;   // swizzled 8-elem chunk within row
    const int NS = HID / 32;
    for (int ks = 0; ks < NS; ++ks) {
        const int cur = ks % 3;
        if (ks == NS - 1) asm volatile("s_waitcnt vmcnt(0)" ::: "memory");
        else              asm volatile("s_waitcnt vmcnt(3)" ::: "memory");
        __builtin_amdgcn_s_barrier();
        asm volatile("" ::: "memory");
        if (ks + 2 < NS) G1_STAGE(ks + 2);
        bf16x8 af[2], bg[2], bu[2];
#pragma unroll
        for (int mi = 0; mi < 2; ++mi)
            af[mi] = *(const bf16x8*)&sA[cur][(wr * 32 + mi * 16 + fr) * 32 + sfo];
#pragma unroll
        for (int ni = 0; ni < 2; ++ni) {
            bg[ni] = *(const bf16x8*)&sB[cur][(wc * 32 + ni * 16 + fr) * 32 + sfo];
            bu[ni] = *(const bf16x8*)&sB[cur][(64 + wc * 32 + ni * 16 + fr) * 32 + sfo];
        }
        __builtin_amdgcn_s_setprio(1);
#pragma unroll
        for (int mi = 0; mi < 2; ++mi)
#pragma unroll
            for (int ni = 0; ni < 2; ++ni) {
                accg[mi][ni] = __builtin_amdgcn_mfma_f32_16x16x32_bf16(af[mi], bg[ni], accg[mi][ni], 0, 0, 0);
                accu[mi][ni] = __builtin_amdgcn_mfma_f32_16x16x32_bf16(af[mi], bu[ni], accu[mi][ni], 0, 0, 0);
            }
        __builtin_amdgcn_s_setprio(0);
        asm volatile("" ::: "memory");
    }
#undef G1_STAGE

#pragma unroll
    for (int mi = 0; mi < 2; ++mi) {
#pragma unroll
        for (int j = 0; j < 4; ++j) {
            const int gr = mt * 64 + wr * 32 + mi * 16 + fq * 4 + j;
            if (gr < cnt) {
#pragma unroll
                for (int ni = 0; ni < 2; ++ni) {
                    const float g = accg[mi][ni][j], u = accu[mi][ni][j];
                    const float s = g / (1.f + expf(-g));
                    act[(size_t)(offs + gr) * ITR + nt * 64 + wc * 32 + ni * 16 + fr] = f2bf(s * u);
                }
            }
        }
    }
}

// ---------------- GEMM2: actb @ w2b[e]^T, fused weighted scatter-add ----------------
__global__ __launch_bounds__(256) void gemm2_kernel(const unsigned short* __restrict__ W2b,
                                                    const unsigned short* __restrict__ actb,
                                                    const int* __restrict__ offsets,
                                                    const int* __restrict__ counts,
                                                    const int* __restrict__ sorted_tok,
                                                    const float* __restrict__ row_w,
                                                    float* __restrict__ out) {
    const int e = blockIdx.z, mt = blockIdx.y, nt = blockIdx.x;
    const int cnt = counts[e];
    if (mt * 64 >= cnt) return;
    const int offs = offsets[e];
    const int tid = threadIdx.x, lane = tid & 63, wid = tid >> 6;
    const int wr = wid >> 1, wc = wid & 1;

    __shared__ unsigned short sA[3][64 * 32];
    __shared__ unsigned short sB[3][128 * 32];

    const int swz = (((tid & 3) ^ ((tid >> 2) & 3))) * 8;
    int ar = mt * 64 + (tid >> 2);
    if (ar >= cnt) ar = cnt - 1;
    const unsigned short* aSrc0 = actb + (size_t)(offs + ar) * ITR + swz;
    const unsigned short* bSrc0 = W2b + ((size_t)e * HID + nt * 128 + (tid >> 2)) * ITR + swz;
    const unsigned short* bSrc1 = bSrc0 + (size_t)64 * ITR;
    const int ldsOff0 = wid * 16 * 32;
    const int ldsOff1 = (64 + wid * 16) * 32;

    f32x4 acc[2][4];
#pragma unroll
    for (int i = 0; i < 2; ++i)
#pragma unroll
        for (int j = 0; j < 4; ++j) acc[i][j] = (f32x4){0.f, 0.f, 0.f, 0.f};

#define G2_STAGE(ks) do {                                  \
        const int k0_ = (ks) * 32;                         \
        unsigned short* a_ = sA[(ks) % 3];                 \
        unsigned short* b_ = sB[(ks) % 3];                 \
        gll16(aSrc0 + k0_, a_ + ldsOff0);                  \
        gll16(bSrc0 + k0_, b_ + ldsOff0);                  \
        gll16(bSrc1 + k0_, b_ + ldsOff1);                  \
    } while (0)

    G2_STAGE(0);
    G2_STAGE(1);

    const int fr = lane & 15, fq = lane >> 4;
    const int sfo = (fq ^ (fr & 3)) * 8;
    const int NS = ITR / 32;
    for (int ks = 0; ks < NS; ++ks) {
        const int cur = ks % 3;
        if (ks == NS - 1) asm volatile("s_waitcnt vmcnt(0)" ::: "memory");
        else              asm volatile("s_waitcnt vmcnt(3)" ::: "memory");
        __builtin_amdgcn_s_barrier();
        asm volatile("" ::: "memory");
        if (ks + 2 < NS) G2_STAGE(ks + 2);
        bf16x8 af[2], bfv[4];
#pragma unroll
        for (int mi = 0; mi < 2; ++mi)
            af[mi] = *(const bf16x8*)&sA[cur][(wr * 32 + mi * 16 + fr) * 32 + sfo];
#pragma unroll
        for (int ni = 0; ni < 4; ++ni)
            bfv[ni] = *(const bf16x8*)&sB[cur][(wc * 64 + ni * 16 + fr) * 32 + sfo];
        __builtin_amdgcn_s_setprio(1);
#pragma unroll
        for (int mi = 0; mi < 2; ++mi)
#pragma unroll
            for (int ni = 0; ni < 4; ++ni)
                acc[mi][ni] = __builtin_amdgcn_mfma_f32_16x16x32_bf16(af[mi], bfv[ni], acc[mi][ni], 0, 0, 0);
        __builtin_amdgcn_s_setprio(0);
        asm volatile("" ::: "memory");
    }
#undef G2_STAGE

#pragma unroll
    for (int mi = 0; mi < 2; ++mi) {
#pragma unroll
        for (int j = 0; j < 4; ++j) {
            const int gr = mt * 64 + wr * 32 + mi * 16 + fq * 4 + j;
            if (gr < cnt) {
                const int pos = offs + gr;
                const int t = sorted_tok[pos];
                const float w = row_w[pos];
#pragma unroll
                for (int ni = 0; ni < 4; ++ni) {
                    const int col = nt * 128 + wc * 64 + ni * 16 + fr;
                    atomicAdd(&out[(size_t)t * HID + col], w * acc[mi][ni][j]);
                }
            }
        }
    }
}

extern "C" void kernel_launch(void* const* d_in, const int* in_sizes, int n_in,
                              void* d_out, int out_size, void* d_ws, size_t ws_size,
                              hipStream_t stream) {
    const float* x   = (const float*)d_in[0];
    const float* gw  = (const float*)d_in[1];
    const float* ws  = (const float*)d_in[2];
    const float* w2s = (const float*)d_in[3];
    float* out = (float*)d_out;

    // ---- workspace layout (disjoint; ~113 MiB total) ----
    char* wsb = (char*)d_ws;
    int*   counts     = (int*)(wsb + 0);
    int*   offsets    = (int*)(wsb + 256);
    int*   cursors    = (int*)(wsb + 512);
    int*   topk_id    = (int*)(wsb + 4096);
    float* topk_w     = (float*)(wsb + 20480);
    int*   sorted_tok = (int*)(wsb + 36864);
    float* row_w      = (float*)(wsb + 53248);
    unsigned short* xb    = (unsigned short*)(wsb + (1u << 20));   // 8 MiB
    unsigned short* actb  = (unsigned short*)(wsb + 9437184);      // 8 MiB
    unsigned short* wsb16 = (unsigned short*)(wsb + 17825792);     // 64 MiB
    unsigned short* w2b   = (unsigned short*)(wsb + 84934656);     // 32 MiB

    zero_counts_kernel<<<1, 64, 0, stream>>>(counts);
    zero_out_kernel<<<out_size / 1024, 256, 0, stream>>>(out);
    cvt_kernel<<<2048, 256, 0, stream>>>(ws,  wsb16, (NEXP * 2 * ITR * HID) / 8);
    cvt_kernel<<<2048, 256, 0, stream>>>(w2s, w2b,   (NEXP * HID * ITR) / 8);
    router_kernel<<<TOKS, 64, 0, stream>>>(x, gw, xb, topk_id, topk_w, counts);
    offsets_kernel<<<1, 64, 0, stream>>>(counts, offsets, cursors);
    assign_kernel<<<NROWS / 256, 256, 0, stream>>>(topk_id, topk_w, cursors, sorted_tok, row_w);
    gemm1_kernel<<<dim3(16, 32, NEXP), 256, 0, stream>>>(wsb16, xb, offsets, counts, sorted_tok, actb);
    gemm2_kernel<<<dim3(16, 32, NEXP), 256, 0, stream>>>(w2b, actb, offsets, counts, sorted_tok, row_w, out);
}

// Round 9
// 248.553 us; speedup vs baseline: 1.2256x; 1.2256x over previous
//
#include <hip/hip_runtime.h>
#include <hip/hip_bf16.h>
#include <stdint.h>

#define TOKS  2048
#define HID   2048
#define ITR   1024
#define NEXP  8
#define NROWS 4096   // TOKS * TOP_K

typedef __attribute__((ext_vector_type(4))) float f32x4;
typedef __attribute__((ext_vector_type(8))) __bf16 bf16x8;
typedef __attribute__((ext_vector_type(8))) unsigned short u16x8;
typedef __attribute__((ext_vector_type(4))) unsigned short u16x4;

__device__ __forceinline__ unsigned short f2bf(float f) {
    union { float f; uint32_t u; } c; c.f = f;
    return (unsigned short)((c.u + 0x7FFFu + ((c.u >> 16) & 1u)) >> 16);
}

// async global->LDS, 16B per lane. LDS dest = wave-uniform base + lane*16 (HW).
__device__ __forceinline__ void gll16(const unsigned short* g, unsigned short* l) {
    __builtin_amdgcn_global_load_lds(
        (const __attribute__((address_space(1))) unsigned int*)g,
        (__attribute__((address_space(3))) unsigned int*)l,
        16, 0, 0);
}

// ---------------- init ----------------
__global__ __launch_bounds__(64) void zero_counts_kernel(int* counts) {
    if (threadIdx.x < NEXP) counts[threadIdx.x] = 0;
}

__global__ __launch_bounds__(256) void zero_out_kernel(float* __restrict__ out) {
    const int i = (blockIdx.x * 256 + threadIdx.x) * 4;
    *(f32x4*)&out[i] = (f32x4){0.f, 0.f, 0.f, 0.f};
}

// ---------------- fp32 -> bf16 convert ----------------
__global__ __launch_bounds__(256) void cvt_kernel(const float* __restrict__ src,
                                                  unsigned short* __restrict__ dst,
                                                  int n8) {
    int i = blockIdx.x * 256 + threadIdx.x;
    const int stride = gridDim.x * 256;
    for (; i < n8; i += stride) {
        const f32x4* p = (const f32x4*)(src + (size_t)i * 8);
        f32x4 a = p[0], b = p[1];
        u16x8 o;
#pragma unroll
        for (int j = 0; j < 4; ++j) { o[j] = f2bf(a[j]); o[4 + j] = f2bf(b[j]); }
        *(u16x8*)(dst + (size_t)i * 8) = o;
    }
}

// ---------------- router (vectorized; also emits bf16 copy of x) ----------------
__global__ __launch_bounds__(64) void router_kernel(const float* __restrict__ x,
                                                    const float* __restrict__ gw,
                                                    unsigned short* __restrict__ xb,
                                                    int* __restrict__ topk_id,
                                                    float* __restrict__ topk_w,
                                                    int* __restrict__ counts) {
    const int t = blockIdx.x;
    const int lane = threadIdx.x;
    float acc[NEXP];
#pragma unroll
    for (int e = 0; e < NEXP; ++e) acc[e] = 0.f;
    const float* xr = x + (size_t)t * HID;
    unsigned short* xbr = xb + (size_t)t * HID;
    for (int s4 = lane; s4 < HID / 4; s4 += 64) {
        const f32x4 xv = *(const f32x4*)(xr + s4 * 4);
        u16x4 o;
#pragma unroll
        for (int j = 0; j < 4; ++j) o[j] = f2bf(xv[j]);
        *(u16x4*)(xbr + s4 * 4) = o;
#pragma unroll
        for (int e = 0; e < NEXP; ++e) {
            const f32x4 gv = *(const f32x4*)(gw + e * HID + s4 * 4);
            acc[e] += xv[0] * gv[0] + xv[1] * gv[1] + xv[2] * gv[2] + xv[3] * gv[3];
        }
    }
#pragma unroll
    for (int e = 0; e < NEXP; ++e) {
        float v = acc[e];
        for (int off = 32; off > 0; off >>= 1) v += __shfl_down(v, off, 64);
        acc[e] = v;
    }
    if (lane == 0) {
        float m0 = -1e30f, m1 = -1e30f; int i0 = 0, i1 = 0;
#pragma unroll
        for (int e = 0; e < NEXP; ++e) {
            float v = acc[e];
            if (v > m0) { m1 = m0; i1 = i0; m0 = v; i0 = e; }
            else if (v > m1) { m1 = v; i1 = e; }
        }
        float w0 = 1.f / (1.f + expf(m1 - m0));
        float w1 = 1.f - w0;
        topk_id[t * 2] = i0; topk_id[t * 2 + 1] = i1;
        topk_w[t * 2] = w0;  topk_w[t * 2 + 1] = w1;
        atomicAdd(&counts[i0], 1);
        atomicAdd(&counts[i1], 1);
    }
}

__global__ void offsets_kernel(const int* __restrict__ counts,
                               int* __restrict__ offsets,
                               int* __restrict__ cursors) {
    if (threadIdx.x == 0) {
        int s = 0;
        for (int e = 0; e < NEXP; ++e) { offsets[e] = s; cursors[e] = s; s += counts[e]; }
        offsets[NEXP] = s;
    }
}

__global__ __launch_bounds__(256) void assign_kernel(const int* __restrict__ topk_id,
                                                     const float* __restrict__ topk_w,
                                                     int* __restrict__ cursors,
                                                     int* __restrict__ sorted_tok,
                                                     float* __restrict__ row_w) {
    const int p = blockIdx.x * 256 + threadIdx.x;
    if (p >= NROWS) return;
    const int e = topk_id[p];
    const int pos = atomicAdd(&cursors[e], 1);
    sorted_tok[pos] = p >> 1;
    row_w[pos] = topk_w[p];
}

// ---------------- GEMM1: gathered xb @ wsb[e]^T, fused SiLU*up ----------------
// 128 A-rows x (64 gate + 64 up) B-rows, BK=32, 8 WAVES (512 thr), triple-buffer
// (48 KB), one barrier + counted vmcnt(2) per K-step. Wave (wr,wc) = 2x4 grid:
// 4 M-frags x 1 gate-frag + 1 up-frag = 8 MFMA/wave/step.
__global__ __launch_bounds__(512) void gemm1_kernel(const unsigned short* __restrict__ Wb,
                                                    const unsigned short* __restrict__ Xb,
                                                    const int* __restrict__ offsets,
                                                    const int* __restrict__ counts,
                                                    const int* __restrict__ sorted_tok,
                                                    unsigned short* __restrict__ act) {
    const int e = blockIdx.z, mt = blockIdx.y, nt = blockIdx.x;
    const int cnt = counts[e];
    if (mt * 128 >= cnt) return;
    const int offs = offsets[e];
    const int tid = threadIdx.x, lane = tid & 63, wid = tid >> 6;
    const int wr = wid >> 2, wc = wid & 3;

    __shared__ unsigned short sA[3][128 * 32];
    __shared__ unsigned short sB[3][128 * 32];

    // staging: thread covers tile-row tid>>2 (0..127), swizzled 8-elem chunk
    const int srow = tid >> 2;
    const int swz = (((tid & 3) ^ (srow & 3))) * 8;
    int ar = mt * 128 + srow;
    if (ar >= cnt) ar = cnt - 1;
    const int tok = sorted_tok[offs + ar];
    const unsigned short* aSrc = Xb + (size_t)tok * HID + swz;
    const unsigned short* wBase = Wb + (size_t)e * (2 * ITR) * HID;
    const int wrow = (srow < 64) ? (nt * 64 + srow) : (ITR + nt * 64 + (srow - 64));
    const unsigned short* bSrc = wBase + (size_t)wrow * HID + swz;
    const int ldsOff = wid * 16 * 32;   // wave stages 16 rows (1 KB)

    f32x4 accg[4], accu[4];
#pragma unroll
    for (int i = 0; i < 4; ++i) {
        accg[i] = (f32x4){0.f, 0.f, 0.f, 0.f};
        accu[i] = (f32x4){0.f, 0.f, 0.f, 0.f};
    }

#define G1_STAGE(ks) do {                                  \
        const int k0_ = (ks) * 32;                         \
        gll16(aSrc + k0_, sA[(ks) % 3] + ldsOff);          \
        gll16(bSrc + k0_, sB[(ks) % 3] + ldsOff);          \
    } while (0)

    G1_STAGE(0);
    G1_STAGE(1);

    const int fr = lane & 15, fq = lane >> 4;
    const int sfo = (fq ^ (fr & 3)) * 8;   // swizzled read chunk
    const int NS = HID / 32;
    for (int ks = 0; ks < NS; ++ks) {
        const int cur = ks % 3;
        if (ks == NS - 1) asm volatile("s_waitcnt vmcnt(0)" ::: "memory");
        else              asm volatile("s_waitcnt vmcnt(2)" ::: "memory");
        __builtin_amdgcn_s_barrier();
        asm volatile("" ::: "memory");
        if (ks + 2 < NS) G1_STAGE(ks + 2);
        bf16x8 af[4], bg, bu;
#pragma unroll
        for (int mi = 0; mi < 4; ++mi)
            af[mi] = *(const bf16x8*)&sA[cur][(wr * 64 + mi * 16 + fr) * 32 + sfo];
        bg = *(const bf16x8*)&sB[cur][(wc * 16 + fr) * 32 + sfo];
        bu = *(const bf16x8*)&sB[cur][(64 + wc * 16 + fr) * 32 + sfo];
        __builtin_amdgcn_s_setprio(1);
#pragma unroll
        for (int mi = 0; mi < 4; ++mi) {
            accg[mi] = __builtin_amdgcn_mfma_f32_16x16x32_bf16(af[mi], bg, accg[mi], 0, 0, 0);
            accu[mi] = __builtin_amdgcn_mfma_f32_16x16x32_bf16(af[mi], bu, accu[mi], 0, 0, 0);
        }
        __builtin_amdgcn_s_setprio(0);
        asm volatile("" ::: "memory");
    }
#undef G1_STAGE

#pragma unroll
    for (int mi = 0; mi < 4; ++mi) {
#pragma unroll
        for (int j = 0; j < 4; ++j) {
            const int gr = mt * 128 + wr * 64 + mi * 16 + fq * 4 + j;
            if (gr < cnt) {
                const float g = accg[mi][j], u = accu[mi][j];
                const float s = g / (1.f + expf(-g));
                act[(size_t)(offs + gr) * ITR + nt * 64 + wc * 16 + fr] = f2bf(s * u);
            }
        }
    }
}

// ---------------- GEMM2: actb @ w2b[e]^T, fused weighted scatter-add ----------------
// 128 A-rows x 128 B-rows, 8 waves; wave (wr,wc)=2x4: 4 M-frags x 2 N-frags.
__global__ __launch_bounds__(512) void gemm2_kernel(const unsigned short* __restrict__ W2b,
                                                    const unsigned short* __restrict__ actb,
                                                    const int* __restrict__ offsets,
                                                    const int* __restrict__ counts,
                                                    const int* __restrict__ sorted_tok,
                                                    const float* __restrict__ row_w,
                                                    float* __restrict__ out) {
    const int e = blockIdx.z, mt = blockIdx.y, nt = blockIdx.x;
    const int cnt = counts[e];
    if (mt * 128 >= cnt) return;
    const int offs = offsets[e];
    const int tid = threadIdx.x, lane = tid & 63, wid = tid >> 6;
    const int wr = wid >> 2, wc = wid & 3;

    __shared__ unsigned short sA[3][128 * 32];
    __shared__ unsigned short sB[3][128 * 32];

    const int srow = tid >> 2;
    const int swz = (((tid & 3) ^ (srow & 3))) * 8;
    int ar = mt * 128 + srow;
    if (ar >= cnt) ar = cnt - 1;
    const unsigned short* aSrc = actb + (size_t)(offs + ar) * ITR + swz;
    const unsigned short* bSrc = W2b + ((size_t)e * HID + nt * 128 + srow) * ITR + swz;
    const int ldsOff = wid * 16 * 32;

    f32x4 acc[4][2];
#pragma unroll
    for (int i = 0; i < 4; ++i)
#pragma unroll
        for (int j = 0; j < 2; ++j) acc[i][j] = (f32x4){0.f, 0.f, 0.f, 0.f};

#define G2_STAGE(ks) do {                                  \
        const int k0_ = (ks) * 32;                         \
        gll16(aSrc + k0_, sA[(ks) % 3] + ldsOff);          \
        gll16(bSrc + k0_, sB[(ks) % 3] + ldsOff);          \
    } while (0)

    G2_STAGE(0);
    G2_STAGE(1);

    const int fr = lane & 15, fq = lane >> 4;
    const int sfo = (fq ^ (fr & 3)) * 8;
    const int NS = ITR / 32;
    for (int ks = 0; ks < NS; ++ks) {
        const int cur = ks % 3;
        if (ks == NS - 1) asm volatile("s_waitcnt vmcnt(0)" ::: "memory");
        else              asm volatile("s_waitcnt vmcnt(2)" ::: "memory");
        __builtin_amdgcn_s_barrier();
        asm volatile("" ::: "memory");
        if (ks + 2 < NS) G2_STAGE(ks + 2);
        bf16x8 af[4], bfv[2];
#pragma unroll
        for (int mi = 0; mi < 4; ++mi)
            af[mi] = *(const bf16x8*)&sA[cur][(wr * 64 + mi * 16 + fr) * 32 + sfo];
#pragma unroll
        for (int ni = 0; ni < 2; ++ni)
            bfv[ni] = *(const bf16x8*)&sB[cur][(wc * 32 + ni * 16 + fr) * 32 + sfo];
        __builtin_amdgcn_s_setprio(1);
#pragma unroll
        for (int mi = 0; mi < 4; ++mi)
#pragma unroll
            for (int ni = 0; ni < 2; ++ni)
                acc[mi][ni] = __builtin_amdgcn_mfma_f32_16x16x32_bf16(af[mi], bfv[ni], acc[mi][ni], 0, 0, 0);
        __builtin_amdgcn_s_setprio(0);
        asm volatile("" ::: "memory");
    }
#undef G2_STAGE

#pragma unroll
    for (int mi = 0; mi < 4; ++mi) {
#pragma unroll
        for (int j = 0; j < 4; ++j) {
            const int gr = mt * 128 + wr * 64 + mi * 16 + fq * 4 + j;
            if (gr < cnt) {
                const int pos = offs + gr;
                const int t = sorted_tok[pos];
                const float w = row_w[pos];
#pragma unroll
                for (int ni = 0; ni < 2; ++ni) {
                    const int col = nt * 128 + wc * 32 + ni * 16 + fr;
                    atomicAdd(&out[(size_t)t * HID + col], w * acc[mi][ni][j]);
                }
            }
        }
    }
}

extern "C" void kernel_launch(void* const* d_in, const int* in_sizes, int n_in,
                              void* d_out, int out_size, void* d_ws, size_t ws_size,
                              hipStream_t stream) {
    const float* x   = (const float*)d_in[0];
    const float* gw  = (const float*)d_in[1];
    const float* ws  = (const float*)d_in[2];
    const float* w2s = (const float*)d_in[3];
    float* out = (float*)d_out;

    // ---- workspace layout (disjoint; ~113 MiB total) ----
    char* wsb = (char*)d_ws;
    int*   counts     = (int*)(wsb + 0);
    int*   offsets    = (int*)(wsb + 256);
    int*   cursors    = (int*)(wsb + 512);
    int*   topk_id    = (int*)(wsb + 4096);
    float* topk_w     = (float*)(wsb + 20480);
    int*   sorted_tok = (int*)(wsb + 36864);
    float* row_w      = (float*)(wsb + 53248);
    unsigned short* xb    = (unsigned short*)(wsb + (1u << 20));   // 8 MiB
    unsigned short* actb  = (unsigned short*)(wsb + 9437184);      // 8 MiB
    unsigned short* wsb16 = (unsigned short*)(wsb + 17825792);     // 64 MiB
    unsigned short* w2b   = (unsigned short*)(wsb + 84934656);     // 32 MiB

    zero_counts_kernel<<<1, 64, 0, stream>>>(counts);
    zero_out_kernel<<<out_size / 1024, 256, 0, stream>>>(out);
    cvt_kernel<<<2048, 256, 0, stream>>>(ws,  wsb16, (NEXP * 2 * ITR * HID) / 8);
    cvt_kernel<<<2048, 256, 0, stream>>>(w2s, w2b,   (NEXP * HID * ITR) / 8);
    router_kernel<<<TOKS, 64, 0, stream>>>(x, gw, xb, topk_id, topk_w, counts);
    offsets_kernel<<<1, 64, 0, stream>>>(counts, offsets, cursors);
    assign_kernel<<<NROWS / 256, 256, 0, stream>>>(topk_id, topk_w, cursors, sorted_tok, row_w);
    gemm1_kernel<<<dim3(16, 16, NEXP), 512, 0, stream>>>(wsb16, xb, offsets, counts, sorted_tok, actb);
    gemm2_kernel<<<dim3(16, 16, NEXP), 512, 0, stream>>>(w2b, actb, offsets, counts, sorted_tok, row_w, out);
}

// Round 10
// 237.470 us; speedup vs baseline: 1.2828x; 1.0467x over previous
//
#include <hip/hip_runtime.h>
#include <hip/hip_bf16.h>
#include <stdint.h>

#define TOKS  2048
#define HID   2048
#define ITR   1024
#define NEXP  8
#define NROWS 4096   // TOKS * TOP_K

typedef __attribute__((ext_vector_type(4))) float f32x4;
typedef __attribute__((ext_vector_type(8))) __bf16 bf16x8;
typedef __attribute__((ext_vector_type(8))) unsigned short u16x8;
typedef __attribute__((ext_vector_type(4))) unsigned short u16x4;

__device__ __forceinline__ unsigned short f2bf(float f) {
    union { float f; uint32_t u; } c; c.f = f;
    return (unsigned short)((c.u + 0x7FFFu + ((c.u >> 16) & 1u)) >> 16);
}

// async global->LDS, 16B per lane. LDS dest = wave-uniform base + lane*16 (HW).
__device__ __forceinline__ void gll16(const unsigned short* g, unsigned short* l) {
    __builtin_amdgcn_global_load_lds(
        (const __attribute__((address_space(1))) unsigned int*)g,
        (__attribute__((address_space(3))) unsigned int*)l,
        16, 0, 0);
}

// ---------------- init ----------------
__global__ __launch_bounds__(64) void zero_counts_kernel(int* counts) {
    if (threadIdx.x < NEXP) counts[threadIdx.x] = 0;
}

__global__ __launch_bounds__(256) void zero_out_kernel(float* __restrict__ out) {
    const int i = (blockIdx.x * 256 + threadIdx.x) * 4;
    *(f32x4*)&out[i] = (f32x4){0.f, 0.f, 0.f, 0.f};
}

// ---------------- fp32 -> bf16 convert ----------------
__global__ __launch_bounds__(256) void cvt_kernel(const float* __restrict__ src,
                                                  unsigned short* __restrict__ dst,
                                                  int n8) {
    int i = blockIdx.x * 256 + threadIdx.x;
    const int stride = gridDim.x * 256;
    for (; i < n8; i += stride) {
        const f32x4* p = (const f32x4*)(src + (size_t)i * 8);
        f32x4 a = p[0], b = p[1];
        u16x8 o;
#pragma unroll
        for (int j = 0; j < 4; ++j) { o[j] = f2bf(a[j]); o[4 + j] = f2bf(b[j]); }
        *(u16x8*)(dst + (size_t)i * 8) = o;
    }
}

// ---------------- router (vectorized; also emits bf16 copy of x) ----------------
__global__ __launch_bounds__(64) void router_kernel(const float* __restrict__ x,
                                                    const float* __restrict__ gw,
                                                    unsigned short* __restrict__ xb,
                                                    int* __restrict__ topk_id,
                                                    float* __restrict__ topk_w,
                                                    int* __restrict__ counts) {
    const int t = blockIdx.x;
    const int lane = threadIdx.x;
    float acc[NEXP];
#pragma unroll
    for (int e = 0; e < NEXP; ++e) acc[e] = 0.f;
    const float* xr = x + (size_t)t * HID;
    unsigned short* xbr = xb + (size_t)t * HID;
    for (int s4 = lane; s4 < HID / 4; s4 += 64) {
        const f32x4 xv = *(const f32x4*)(xr + s4 * 4);
        u16x4 o;
#pragma unroll
        for (int j = 0; j < 4; ++j) o[j] = f2bf(xv[j]);
        *(u16x4*)(xbr + s4 * 4) = o;
#pragma unroll
        for (int e = 0; e < NEXP; ++e) {
            const f32x4 gv = *(const f32x4*)(gw + e * HID + s4 * 4);
            acc[e] += xv[0] * gv[0] + xv[1] * gv[1] + xv[2] * gv[2] + xv[3] * gv[3];
        }
    }
#pragma unroll
    for (int e = 0; e < NEXP; ++e) {
        float v = acc[e];
        for (int off = 32; off > 0; off >>= 1) v += __shfl_down(v, off, 64);
        acc[e] = v;
    }
    if (lane == 0) {
        float m0 = -1e30f, m1 = -1e30f; int i0 = 0, i1 = 0;
#pragma unroll
        for (int e = 0; e < NEXP; ++e) {
            float v = acc[e];
            if (v > m0) { m1 = m0; i1 = i0; m0 = v; i0 = e; }
            else if (v > m1) { m1 = v; i1 = e; }
        }
        float w0 = 1.f / (1.f + expf(m1 - m0));
        float w1 = 1.f - w0;
        topk_id[t * 2] = i0; topk_id[t * 2 + 1] = i1;
        topk_w[t * 2] = w0;  topk_w[t * 2 + 1] = w1;
        atomicAdd(&counts[i0], 1);
        atomicAdd(&counts[i1], 1);
    }
}

__global__ void offsets_kernel(const int* __restrict__ counts,
                               int* __restrict__ offsets,
                               int* __restrict__ cursors) {
    if (threadIdx.x == 0) {
        int s = 0;
        for (int e = 0; e < NEXP; ++e) { offsets[e] = s; cursors[e] = s; s += counts[e]; }
        offsets[NEXP] = s;
    }
}

__global__ __launch_bounds__(256) void assign_kernel(const int* __restrict__ topk_id,
                                                     const float* __restrict__ topk_w,
                                                     int* __restrict__ cursors,
                                                     int* __restrict__ sorted_tok,
                                                     float* __restrict__ row_w) {
    const int p = blockIdx.x * 256 + threadIdx.x;
    if (p >= NROWS) return;
    const int e = topk_id[p];
    const int pos = atomicAdd(&cursors[e], 1);
    sorted_tok[pos] = p >> 1;
    row_w[pos] = topk_w[p];
}

// ---------------- GEMM1: gathered xb @ wsb[e]^T, fused SiLU*up ----------------
// 128 A-rows x (64 gate + 64 up) B-rows, BK=32, 8 waves, triple-buffer,
// counted vmcnt(2), XCD-affine flat grid: expert = blockIdx.x & 7 -> XCD.
__global__ __launch_bounds__(512) void gemm1_kernel(const unsigned short* __restrict__ Wb,
                                                    const unsigned short* __restrict__ Xb,
                                                    const int* __restrict__ offsets,
                                                    const int* __restrict__ counts,
                                                    const int* __restrict__ sorted_tok,
                                                    unsigned short* __restrict__ act) {
    const int b = blockIdx.x;
    const int e = b & 7;          // expert -> XCD (round-robin heuristic)
    const int r = b >> 3;         // 0..255
    const int mt = r >> 4;        // 0..15
    const int nt = r & 15;        // 0..15
    const int cnt = counts[e];
    if (mt * 128 >= cnt) return;
    const int offs = offsets[e];
    const int tid = threadIdx.x, lane = tid & 63, wid = tid >> 6;
    const int wr = wid >> 2, wc = wid & 3;

    __shared__ unsigned short sA[3][128 * 32];
    __shared__ unsigned short sB[3][128 * 32];

    const int srow = tid >> 2;
    const int swz = (((tid & 3) ^ (srow & 3))) * 8;
    int ar = mt * 128 + srow;
    if (ar >= cnt) ar = cnt - 1;
    const int tok = sorted_tok[offs + ar];
    const unsigned short* aSrc = Xb + (size_t)tok * HID + swz;
    const unsigned short* wBase = Wb + (size_t)e * (2 * ITR) * HID;
    const int wrow = (srow < 64) ? (nt * 64 + srow) : (ITR + nt * 64 + (srow - 64));
    const unsigned short* bSrc = wBase + (size_t)wrow * HID + swz;
    const int ldsOff = wid * 16 * 32;

    f32x4 accg[4], accu[4];
#pragma unroll
    for (int i = 0; i < 4; ++i) {
        accg[i] = (f32x4){0.f, 0.f, 0.f, 0.f};
        accu[i] = (f32x4){0.f, 0.f, 0.f, 0.f};
    }

#define G1_STAGE(ks) do {                                  \
        const int k0_ = (ks) * 32;                         \
        gll16(aSrc + k0_, sA[(ks) % 3] + ldsOff);          \
        gll16(bSrc + k0_, sB[(ks) % 3] + ldsOff);          \
    } while (0)

    G1_STAGE(0);
    G1_STAGE(1);

    const int fr = lane & 15, fq = lane >> 4;
    const int sfo = (fq ^ (fr & 3)) * 8;
    const int NS = HID / 32;
    for (int ks = 0; ks < NS; ++ks) {
        const int cur = ks % 3;
        if (ks == NS - 1) asm volatile("s_waitcnt vmcnt(0)" ::: "memory");
        else              asm volatile("s_waitcnt vmcnt(2)" ::: "memory");
        __builtin_amdgcn_s_barrier();
        asm volatile("" ::: "memory");
        if (ks + 2 < NS) G1_STAGE(ks + 2);
        bf16x8 af[4], bg, bu;
#pragma unroll
        for (int mi = 0; mi < 4; ++mi)
            af[mi] = *(const bf16x8*)&sA[cur][(wr * 64 + mi * 16 + fr) * 32 + sfo];
        bg = *(const bf16x8*)&sB[cur][(wc * 16 + fr) * 32 + sfo];
        bu = *(const bf16x8*)&sB[cur][(64 + wc * 16 + fr) * 32 + sfo];
        __builtin_amdgcn_s_setprio(1);
#pragma unroll
        for (int mi = 0; mi < 4; ++mi) {
            accg[mi] = __builtin_amdgcn_mfma_f32_16x16x32_bf16(af[mi], bg, accg[mi], 0, 0, 0);
            accu[mi] = __builtin_amdgcn_mfma_f32_16x16x32_bf16(af[mi], bu, accu[mi], 0, 0, 0);
        }
        __builtin_amdgcn_s_setprio(0);
        asm volatile("" ::: "memory");
    }
#undef G1_STAGE

#pragma unroll
    for (int mi = 0; mi < 4; ++mi) {
#pragma unroll
        for (int j = 0; j < 4; ++j) {
            const int gr = mt * 128 + wr * 64 + mi * 16 + fq * 4 + j;
            if (gr < cnt) {
                const float g = accg[mi][j], u = accu[mi][j];
                const float s = g / (1.f + expf(-g));
                act[(size_t)(offs + gr) * ITR + nt * 64 + wc * 16 + fr] = f2bf(s * u);
            }
        }
    }
}

// ---------------- GEMM2: actb @ w2b[e]^T, fused weighted scatter-add ----------------
__global__ __launch_bounds__(512) void gemm2_kernel(const unsigned short* __restrict__ W2b,
                                                    const unsigned short* __restrict__ actb,
                                                    const int* __restrict__ offsets,
                                                    const int* __restrict__ counts,
                                                    const int* __restrict__ sorted_tok,
                                                    const float* __restrict__ row_w,
                                                    float* __restrict__ out) {
    const int b = blockIdx.x;
    const int e = b & 7;
    const int r = b >> 3;
    const int mt = r >> 4;
    const int nt = r & 15;
    const int cnt = counts[e];
    if (mt * 128 >= cnt) return;
    const int offs = offsets[e];
    const int tid = threadIdx.x, lane = tid & 63, wid = tid >> 6;
    const int wr = wid >> 2, wc = wid & 3;

    __shared__ unsigned short sA[3][128 * 32];
    __shared__ unsigned short sB[3][128 * 32];

    const int srow = tid >> 2;
    const int swz = (((tid & 3) ^ (srow & 3))) * 8;
    int ar = mt * 128 + srow;
    if (ar >= cnt) ar = cnt - 1;
    const unsigned short* aSrc = actb + (size_t)(offs + ar) * ITR + swz;
    const unsigned short* bSrc = W2b + ((size_t)e * HID + nt * 128 + srow) * ITR + swz;
    const int ldsOff = wid * 16 * 32;

    f32x4 acc[4][2];
#pragma unroll
    for (int i = 0; i < 4; ++i)
#pragma unroll
        for (int j = 0; j < 2; ++j) acc[i][j] = (f32x4){0.f, 0.f, 0.f, 0.f};

#define G2_STAGE(ks) do {                                  \
        const int k0_ = (ks) * 32;                         \
        gll16(aSrc + k0_, sA[(ks) % 3] + ldsOff);          \
        gll16(bSrc + k0_, sB[(ks) % 3] + ldsOff);          \
    } while (0)

    G2_STAGE(0);
    G2_STAGE(1);

    const int fr = lane & 15, fq = lane >> 4;
    const int sfo = (fq ^ (fr & 3)) * 8;
    const int NS = ITR / 32;
    for (int ks = 0; ks < NS; ++ks) {
        const int cur = ks % 3;
        if (ks == NS - 1) asm volatile("s_waitcnt vmcnt(0)" ::: "memory");
        else              asm volatile("s_waitcnt vmcnt(2)" ::: "memory");
        __builtin_amdgcn_s_barrier();
        asm volatile("" ::: "memory");
        if (ks + 2 < NS) G2_STAGE(ks + 2);
        bf16x8 af[4], bfv[2];
#pragma unroll
        for (int mi = 0; mi < 4; ++mi)
            af[mi] = *(const bf16x8*)&sA[cur][(wr * 64 + mi * 16 + fr) * 32 + sfo];
#pragma unroll
        for (int ni = 0; ni < 2; ++ni)
            bfv[ni] = *(const bf16x8*)&sB[cur][(wc * 32 + ni * 16 + fr) * 32 + sfo];
        __builtin_amdgcn_s_setprio(1);
#pragma unroll
        for (int mi = 0; mi < 4; ++mi)
#pragma unroll
            for (int ni = 0; ni < 2; ++ni)
                acc[mi][ni] = __builtin_amdgcn_mfma_f32_16x16x32_bf16(af[mi], bfv[ni], acc[mi][ni], 0, 0, 0);
        __builtin_amdgcn_s_setprio(0);
        asm volatile("" ::: "memory");
    }
#undef G2_STAGE

#pragma unroll
    for (int mi = 0; mi < 4; ++mi) {
#pragma unroll
        for (int j = 0; j < 4; ++j) {
            const int gr = mt * 128 + wr * 64 + mi * 16 + fq * 4 + j;
            if (gr < cnt) {
                const int pos = offs + gr;
                const int t = sorted_tok[pos];
                const float w = row_w[pos];
#pragma unroll
                for (int ni = 0; ni < 2; ++ni) {
                    const int col = nt * 128 + wc * 32 + ni * 16 + fr;
                    atomicAdd(&out[(size_t)t * HID + col], w * acc[mi][ni][j]);
                }
            }
        }
    }
}

extern "C" void kernel_launch(void* const* d_in, const int* in_sizes, int n_in,
                              void* d_out, int out_size, void* d_ws, size_t ws_size,
                              hipStream_t stream) {
    const float* x   = (const float*)d_in[0];
    const float* gw  = (const float*)d_in[1];
    const float* ws  = (const float*)d_in[2];
    const float* w2s = (const float*)d_in[3];
    float* out = (float*)d_out;

    // ---- workspace layout (disjoint; ~113 MiB total) ----
    char* wsb = (char*)d_ws;
    int*   counts     = (int*)(wsb + 0);
    int*   offsets    = (int*)(wsb + 256);
    int*   cursors    = (int*)(wsb + 512);
    int*   topk_id    = (int*)(wsb + 4096);
    float* topk_w     = (float*)(wsb + 20480);
    int*   sorted_tok = (int*)(wsb + 36864);
    float* row_w      = (float*)(wsb + 53248);
    unsigned short* xb    = (unsigned short*)(wsb + (1u << 20));   // 8 MiB
    unsigned short* actb  = (unsigned short*)(wsb + 9437184);      // 8 MiB
    unsigned short* wsb16 = (unsigned short*)(wsb + 17825792);     // 64 MiB
    unsigned short* w2b   = (unsigned short*)(wsb + 84934656);     // 32 MiB

    zero_counts_kernel<<<1, 64, 0, stream>>>(counts);
    zero_out_kernel<<<out_size / 1024, 256, 0, stream>>>(out);
    cvt_kernel<<<2048, 256, 0, stream>>>(ws,  wsb16, (NEXP * 2 * ITR * HID) / 8);
    cvt_kernel<<<2048, 256, 0, stream>>>(w2s, w2b,   (NEXP * HID * ITR) / 8);
    router_kernel<<<TOKS, 64, 0, stream>>>(x, gw, xb, topk_id, topk_w, counts);
    offsets_kernel<<<1, 64, 0, stream>>>(counts, offsets, cursors);
    assign_kernel<<<NROWS / 256, 256, 0, stream>>>(topk_id, topk_w, cursors, sorted_tok, row_w);
    gemm1_kernel<<<2048, 512, 0, stream>>>(wsb16, xb, offsets, counts, sorted_tok, actb);
    gemm2_kernel<<<2048, 512, 0, stream>>>(w2b, actb, offsets, counts, sorted_tok, row_w, out);
}

// Round 11
// 174.864 us; speedup vs baseline: 1.7421x; 1.3580x over previous
//
#include <hip/hip_runtime.h>
#include <hip/hip_bf16.h>
#include <stdint.h>

#define TOKS  2048
#define HID   2048
#define ITR   1024
#define NEXP  8
#define NROWS 4096   // TOKS * TOP_K

typedef __attribute__((ext_vector_type(4))) float f32x4;
typedef __attribute__((ext_vector_type(8))) __bf16 bf16x8;
typedef __attribute__((ext_vector_type(8))) unsigned short u16x8;
typedef __attribute__((ext_vector_type(4))) unsigned short u16x4;

__device__ __forceinline__ unsigned short f2bf(float f) {
    union { float f; uint32_t u; } c; c.f = f;
    return (unsigned short)((c.u + 0x7FFFu + ((c.u >> 16) & 1u)) >> 16);
}

// async global->LDS, 16B per lane. LDS dest = wave-uniform base + lane*16 (HW).
__device__ __forceinline__ void gll16(const unsigned short* g, unsigned short* l) {
    __builtin_amdgcn_global_load_lds(
        (const __attribute__((address_space(1))) unsigned int*)g,
        (__attribute__((address_space(3))) unsigned int*)l,
        16, 0, 0);
}

// ---------------- prep: cvt ws + cvt w2s + zero out, one kernel ----------------
__global__ __launch_bounds__(256) void prep_kernel(const float* __restrict__ ws,
                                                   const float* __restrict__ w2s,
                                                   float* __restrict__ out,
                                                   unsigned short* __restrict__ da,
                                                   unsigned short* __restrict__ db) {
    const int NA = (NEXP * 2 * ITR * HID) / 8;
    const int NB = (NEXP * HID * ITR) / 8;
    const int NO = (TOKS * HID) / 8;
    const int i0 = blockIdx.x * 256 + threadIdx.x;
    const int stride = gridDim.x * 256;
    for (int k = i0; k < NA; k += stride) {
        const f32x4* p = (const f32x4*)(ws + (size_t)k * 8);
        f32x4 a = p[0], b = p[1];
        u16x8 o;
#pragma unroll
        for (int j = 0; j < 4; ++j) { o[j] = f2bf(a[j]); o[4 + j] = f2bf(b[j]); }
        *(u16x8*)(da + (size_t)k * 8) = o;
    }
    for (int k = i0; k < NB; k += stride) {
        const f32x4* p = (const f32x4*)(w2s + (size_t)k * 8);
        f32x4 a = p[0], b = p[1];
        u16x8 o;
#pragma unroll
        for (int j = 0; j < 4; ++j) { o[j] = f2bf(a[j]); o[4 + j] = f2bf(b[j]); }
        *(u16x8*)(db + (size_t)k * 8) = o;
    }
    const f32x4 z = (f32x4){0.f, 0.f, 0.f, 0.f};
    for (int k = i0; k < NO; k += stride) {
        f32x4* q = (f32x4*)(out + (size_t)k * 8);
        q[0] = z; q[1] = z;
    }
}

// ---------------- router (vectorized; also emits bf16 copy of x) ----------------
__global__ __launch_bounds__(64) void router_kernel(const float* __restrict__ x,
                                                    const float* __restrict__ gw,
                                                    unsigned short* __restrict__ xb,
                                                    int* __restrict__ topk_id,
                                                    float* __restrict__ topk_w) {
    const int t = blockIdx.x;
    const int lane = threadIdx.x;
    float acc[NEXP];
#pragma unroll
    for (int e = 0; e < NEXP; ++e) acc[e] = 0.f;
    const float* xr = x + (size_t)t * HID;
    unsigned short* xbr = xb + (size_t)t * HID;
    for (int s4 = lane; s4 < HID / 4; s4 += 64) {
        const f32x4 xv = *(const f32x4*)(xr + s4 * 4);
        u16x4 o;
#pragma unroll
        for (int j = 0; j < 4; ++j) o[j] = f2bf(xv[j]);
        *(u16x4*)(xbr + s4 * 4) = o;
#pragma unroll
        for (int e = 0; e < NEXP; ++e) {
            const f32x4 gv = *(const f32x4*)(gw + e * HID + s4 * 4);
            acc[e] += xv[0] * gv[0] + xv[1] * gv[1] + xv[2] * gv[2] + xv[3] * gv[3];
        }
    }
#pragma unroll
    for (int e = 0; e < NEXP; ++e) {
        float v = acc[e];
        for (int off = 32; off > 0; off >>= 1) v += __shfl_down(v, off, 64);
        acc[e] = v;
    }
    if (lane == 0) {
        float m0 = -1e30f, m1 = -1e30f; int i0 = 0, i1 = 0;
#pragma unroll
        for (int e = 0; e < NEXP; ++e) {
            float v = acc[e];
            if (v > m0) { m1 = m0; i1 = i0; m0 = v; i0 = e; }
            else if (v > m1) { m1 = v; i1 = e; }
        }
        float w0 = 1.f / (1.f + expf(m1 - m0));
        float w1 = 1.f - w0;
        topk_id[t * 2] = i0; topk_id[t * 2 + 1] = i1;
        topk_w[t * 2] = w0;  topk_w[t * 2 + 1] = w1;
    }
}

// ---------------- deterministic single-block sort-by-expert ----------------
// Replaces zero_counts + offsets + assign. Scan-based, no atomics.
__global__ __launch_bounds__(512) void sort_kernel(const int* __restrict__ topk_id,
                                                   const float* __restrict__ topk_w,
                                                   int* __restrict__ sorted_tok,
                                                   float* __restrict__ row_w,
                                                   int* __restrict__ offsets,
                                                   int* __restrict__ counts) {
    __shared__ int sc[512 * NEXP];
    __shared__ int base[NEXP + 1];
    const int t = threadIdx.x;
    int ids[8];
    int* myrow = &sc[t * NEXP];
#pragma unroll
    for (int e = 0; e < NEXP; ++e) myrow[e] = 0;
#pragma unroll
    for (int j = 0; j < 8; ++j) { ids[j] = topk_id[t * 8 + j]; myrow[ids[j]]++; }
    __syncthreads();
    // Hillis-Steele inclusive scan over threads, all 8 expert columns
    for (int d = 1; d < 512; d <<= 1) {
        int add[NEXP];
        const bool act = (t >= d);
#pragma unroll
        for (int e = 0; e < NEXP; ++e) add[e] = act ? sc[(t - d) * NEXP + e] : 0;
        __syncthreads();
        if (act) {
#pragma unroll
            for (int e = 0; e < NEXP; ++e) sc[t * NEXP + e] += add[e];
        }
        __syncthreads();
    }
    if (t == 0) {
        int s = 0;
        for (int e = 0; e < NEXP; ++e) {
            const int tot = sc[511 * NEXP + e];
            base[e] = s; offsets[e] = s; counts[e] = tot; s += tot;
        }
        base[NEXP] = s; offsets[NEXP] = s;
    }
    __syncthreads();
    int own[NEXP];
#pragma unroll
    for (int e = 0; e < NEXP; ++e) {
        int c = 0;
#pragma unroll
        for (int j = 0; j < 8; ++j) c += (ids[j] == e) ? 1 : 0;
        own[e] = c;
    }
#pragma unroll
    for (int e = 0; e < NEXP; ++e) myrow[e] = base[e] + myrow[e] - own[e];
#pragma unroll
    for (int j = 0; j < 8; ++j) {
        const int p = t * 8 + j;
        const int pos = myrow[ids[j]]++;
        sorted_tok[pos] = p >> 1;
        row_w[pos] = topk_w[p];
    }
}

// ---------------- GEMM1: gathered xb @ wsb[e]^T, fused SiLU*up ----------------
// 128 A-rows x (64 gate + 64 up) B-rows, BK=32, 8 waves, triple-buffer,
// counted vmcnt(2), XCD-affine flat grid: expert = blockIdx.x & 7 -> XCD.
__global__ __launch_bounds__(512) void gemm1_kernel(const unsigned short* __restrict__ Wb,
                                                    const unsigned short* __restrict__ Xb,
                                                    const int* __restrict__ offsets,
                                                    const int* __restrict__ counts,
                                                    const int* __restrict__ sorted_tok,
                                                    unsigned short* __restrict__ act) {
    const int b = blockIdx.x;
    const int e = b & 7;
    const int r = b >> 3;
    const int mt = r >> 4;
    const int nt = r & 15;
    const int cnt = counts[e];
    if (mt * 128 >= cnt) return;
    const int offs = offsets[e];
    const int tid = threadIdx.x, lane = tid & 63, wid = tid >> 6;
    const int wr = wid >> 2, wc = wid & 3;

    __shared__ unsigned short sA[3][128 * 32];
    __shared__ unsigned short sB[3][128 * 32];

    const int srow = tid >> 2;
    const int swz = (((tid & 3) ^ (srow & 3))) * 8;
    int ar = mt * 128 + srow;
    if (ar >= cnt) ar = cnt - 1;
    const int tok = sorted_tok[offs + ar];
    const unsigned short* aSrc = Xb + (size_t)tok * HID + swz;
    const unsigned short* wBase = Wb + (size_t)e * (2 * ITR) * HID;
    const int wrow = (srow < 64) ? (nt * 64 + srow) : (ITR + nt * 64 + (srow - 64));
    const unsigned short* bSrc = wBase + (size_t)wrow * HID + swz;
    const int ldsOff = wid * 16 * 32;

    f32x4 accg[4], accu[4];
#pragma unroll
    for (int i = 0; i < 4; ++i) {
        accg[i] = (f32x4){0.f, 0.f, 0.f, 0.f};
        accu[i] = (f32x4){0.f, 0.f, 0.f, 0.f};
    }

#define G1_STAGE(ks) do {                                  \
        const int k0_ = (ks) * 32;                         \
        gll16(aSrc + k0_, sA[(ks) % 3] + ldsOff);          \
        gll16(bSrc + k0_, sB[(ks) % 3] + ldsOff);          \
    } while (0)

    G1_STAGE(0);
    G1_STAGE(1);

    const int fr = lane & 15, fq = lane >> 4;
    const int sfo = (fq ^ (fr & 3)) * 8;
    const int NS = HID / 32;
    for (int ks = 0; ks < NS; ++ks) {
        const int cur = ks % 3;
        if (ks == NS - 1) asm volatile("s_waitcnt vmcnt(0)" ::: "memory");
        else              asm volatile("s_waitcnt vmcnt(2)" ::: "memory");
        __builtin_amdgcn_s_barrier();
        asm volatile("" ::: "memory");
        if (ks + 2 < NS) G1_STAGE(ks + 2);
        bf16x8 af[4], bg, bu;
#pragma unroll
        for (int mi = 0; mi < 4; ++mi)
            af[mi] = *(const bf16x8*)&sA[cur][(wr * 64 + mi * 16 + fr) * 32 + sfo];
        bg = *(const bf16x8*)&sB[cur][(wc * 16 + fr) * 32 + sfo];
        bu = *(const bf16x8*)&sB[cur][(64 + wc * 16 + fr) * 32 + sfo];
        __builtin_amdgcn_s_setprio(1);
#pragma unroll
        for (int mi = 0; mi < 4; ++mi) {
            accg[mi] = __builtin_amdgcn_mfma_f32_16x16x32_bf16(af[mi], bg, accg[mi], 0, 0, 0);
            accu[mi] = __builtin_amdgcn_mfma_f32_16x16x32_bf16(af[mi], bu, accu[mi], 0, 0, 0);
        }
        __builtin_amdgcn_s_setprio(0);
        asm volatile("" ::: "memory");
    }
#undef G1_STAGE

#pragma unroll
    for (int mi = 0; mi < 4; ++mi) {
#pragma unroll
        for (int j = 0; j < 4; ++j) {
            const int gr = mt * 128 + wr * 64 + mi * 16 + fq * 4 + j;
            if (gr < cnt) {
                const float g = accg[mi][j], u = accu[mi][j];
                const float s = g / (1.f + expf(-g));
                act[(size_t)(offs + gr) * ITR + nt * 64 + wc * 16 + fr] = f2bf(s * u);
            }
        }
    }
}

// ---------------- GEMM2: actb @ w2b[e]^T, fused weighted scatter-add ----------------
__global__ __launch_bounds__(512) void gemm2_kernel(const unsigned short* __restrict__ W2b,
                                                    const unsigned short* __restrict__ actb,
                                                    const int* __restrict__ offsets,
                                                    const int* __restrict__ counts,
                                                    const int* __restrict__ sorted_tok,
                                                    const float* __restrict__ row_w,
                                                    float* __restrict__ out) {
    const int b = blockIdx.x;
    const int e = b & 7;
    const int r = b >> 3;
    const int mt = r >> 4;
    const int nt = r & 15;
    const int cnt = counts[e];
    if (mt * 128 >= cnt) return;
    const int offs = offsets[e];
    const int tid = threadIdx.x, lane = tid & 63, wid = tid >> 6;
    const int wr = wid >> 2, wc = wid & 3;

    __shared__ unsigned short sA[3][128 * 32];
    __shared__ unsigned short sB[3][128 * 32];

    const int srow = tid >> 2;
    const int swz = (((tid & 3) ^ (srow & 3))) * 8;
    int ar = mt * 128 + srow;
    if (ar >= cnt) ar = cnt - 1;
    const unsigned short* aSrc = actb + (size_t)(offs + ar) * ITR + swz;
    const unsigned short* bSrc = W2b + ((size_t)e * HID + nt * 128 + srow) * ITR + swz;
    const int ldsOff = wid * 16 * 32;

    f32x4 acc[4][2];
#pragma unroll
    for (int i = 0; i < 4; ++i)
#pragma unroll
        for (int j = 0; j < 2; ++j) acc[i][j] = (f32x4){0.f, 0.f, 0.f, 0.f};

#define G2_STAGE(ks) do {                                  \
        const int k0_ = (ks) * 32;                         \
        gll16(aSrc + k0_, sA[(ks) % 3] + ldsOff);          \
        gll16(bSrc + k0_, sB[(ks) % 3] + ldsOff);          \
    } while (0)

    G2_STAGE(0);
    G2_STAGE(1);

    const int fr = lane & 15, fq = lane >> 4;
    const int sfo = (fq ^ (fr & 3)) * 8;
    const int NS = ITR / 32;
    for (int ks = 0; ks < NS; ++ks) {
        const int cur = ks % 3;
        if (ks == NS - 1) asm volatile("s_waitcnt vmcnt(0)" ::: "memory");
        else              asm volatile("s_waitcnt vmcnt(2)" ::: "memory");
        __builtin_amdgcn_s_barrier();
        asm volatile("" ::: "memory");
        if (ks + 2 < NS) G2_STAGE(ks + 2);
        bf16x8 af[4], bfv[2];
#pragma unroll
        for (int mi = 0; mi < 4; ++mi)
            af[mi] = *(const bf16x8*)&sA[cur][(wr * 64 + mi * 16 + fr) * 32 + sfo];
#pragma unroll
        for (int ni = 0; ni < 2; ++ni)
            bfv[ni] = *(const bf16x8*)&sB[cur][(wc * 32 + ni * 16 + fr) * 32 + sfo];
        __builtin_amdgcn_s_setprio(1);
#pragma unroll
        for (int mi = 0; mi < 4; ++mi)
#pragma unroll
            for (int ni = 0; ni < 2; ++ni)
                acc[mi][ni] = __builtin_amdgcn_mfma_f32_16x16x32_bf16(af[mi], bfv[ni], acc[mi][ni], 0, 0, 0);
        __builtin_amdgcn_s_setprio(0);
        asm volatile("" ::: "memory");
    }
#undef G2_STAGE

#pragma unroll
    for (int mi = 0; mi < 4; ++mi) {
#pragma unroll
        for (int j = 0; j < 4; ++j) {
            const int gr = mt * 128 + wr * 64 + mi * 16 + fq * 4 + j;
            if (gr < cnt) {
                const int pos = offs + gr;
                const int t = sorted_tok[pos];
                const float w = row_w[pos];
#pragma unroll
                for (int ni = 0; ni < 2; ++ni) {
                    const int col = nt * 128 + wc * 32 + ni * 16 + fr;
                    atomicAdd(&out[(size_t)t * HID + col], w * acc[mi][ni][j]);
                }
            }
        }
    }
}

extern "C" void kernel_launch(void* const* d_in, const int* in_sizes, int n_in,
                              void* d_out, int out_size, void* d_ws, size_t ws_size,
                              hipStream_t stream) {
    const float* x   = (const float*)d_in[0];
    const float* gw  = (const float*)d_in[1];
    const float* ws  = (const float*)d_in[2];
    const float* w2s = (const float*)d_in[3];
    float* out = (float*)d_out;

    // ---- workspace layout (disjoint; ~113 MiB total) ----
    char* wsb = (char*)d_ws;
    int*   counts     = (int*)(wsb + 0);
    int*   offsets    = (int*)(wsb + 256);
    int*   topk_id    = (int*)(wsb + 4096);
    float* topk_w     = (float*)(wsb + 20480);
    int*   sorted_tok = (int*)(wsb + 36864);
    float* row_w      = (float*)(wsb + 53248);
    unsigned short* xb    = (unsigned short*)(wsb + (1u << 20));   // 8 MiB
    unsigned short* actb  = (unsigned short*)(wsb + 9437184);      // 8 MiB
    unsigned short* wsb16 = (unsigned short*)(wsb + 17825792);     // 64 MiB
    unsigned short* w2b   = (unsigned short*)(wsb + 84934656);     // 32 MiB

    prep_kernel<<<2048, 256, 0, stream>>>(ws, w2s, out, wsb16, w2b);
    router_kernel<<<TOKS, 64, 0, stream>>>(x, gw, xb, topk_id, topk_w);
    sort_kernel<<<1, 512, 0, stream>>>(topk_id, topk_w, sorted_tok, row_w, offsets, counts);
    gemm1_kernel<<<2048, 512, 0, stream>>>(wsb16, xb, offsets, counts, sorted_tok, actb);
    gemm2_kernel<<<2048, 512, 0, stream>>>(w2b, actb, offsets, counts, sorted_tok, row_w, out);
}